// Round 9
// baseline (277.245 us; speedup 1.0000x reference)
//
#include <hip/hip_runtime.h>

typedef __bf16 bf16_t;
typedef __bf16 bf16x4 __attribute__((ext_vector_type(4)));
typedef __bf16 bf16x8 __attribute__((ext_vector_type(8)));
typedef float  floatx4 __attribute__((ext_vector_type(4)));

#define MFMA16(a, b, c) __builtin_amdgcn_mfma_f32_16x16x32_bf16((a), (b), (c), 0, 0, 0)

// fp32 element offsets inside d_out
#define ADJ_OFF  2097152
#define MU_OFF   2162688
#define LV_OFF   4259840

#define TWO_LOG2E  2.8853900817779268f
#define HALF_LOG2E 0.7213475204444817f

// tanh(x) given argE2 = 2*log2(e)*x:  tanh = 1 - 2/(2^argE2 + 1).
__device__ __forceinline__ float fast_tanh2(float argE2) {
    float e = __builtin_amdgcn_exp2f(argE2);
    return 1.0f - 2.0f * __builtin_amdgcn_rcpf(e + 1.0f);
}

__device__ __forceinline__ bf16x8 cvt8(const float* p) {
    const floatx4 a = *(const floatx4*)p;
    const floatx4 b = *(const floatx4*)(p + 4);
    bf16x8 r;
#pragma unroll
    for (int j = 0; j < 4; j++) { r[j] = (bf16_t)a[j]; r[4 + j] = (bf16_t)b[j]; }
    return r;
}

// ---------------------------------------------------------------------------
// K0: prep.  Blocks 0-47: LDS-tile transpose-cast of the 3 encoder weights.
// Block 48: wepack = bf16(Wemb*2log2e).  Block 49: bepack = bf16(bemb*2log2e)
// + colc zero + wg1pk (lane-ordered Wg1 MFMA fragments) + pk4 (epilogue tbl).
// ---------------------------------------------------------------------------
__global__ __launch_bounds__(256) void k_prep(
    const float* __restrict__ We, const float* __restrict__ Wm,
    const float* __restrict__ Wl, const float* __restrict__ Wemb,
    const float* __restrict__ bemb, const float* __restrict__ Wg1,
    const float* __restrict__ bg1, const float* __restrict__ Wg2,
    bf16_t* __restrict__ Wt, bf16_t* __restrict__ wepack,
    bf16_t* __restrict__ bepack, int* __restrict__ colc,
    bf16_t* __restrict__ wg1pk, float* __restrict__ pk4) {
    __shared__ float tile[64][65];
    const int b = blockIdx.x, tid = threadIdx.x;
    if (b < 48) {
        const int m = b >> 4, t6 = b & 15;
        const int K0 = (t6 >> 2) << 6, N0 = (t6 & 3) << 6;
        const float* src = (m == 0) ? We : ((m == 1) ? Wm : Wl);
#pragma unroll
        for (int p = 0; p < 16; p++) {
            const int idx = p * 256 + tid;
            tile[idx >> 6][idx & 63] = src[(K0 + (idx >> 6)) * 256 + N0 + (idx & 63)];
        }
        __syncthreads();
        bf16_t* dst = Wt + m * 65536;
#pragma unroll
        for (int p = 0; p < 16; p++) {
            const int idx = p * 256 + tid;
            const int nn = idx >> 6, kk = idx & 63;
            dst[(N0 + nn) * 256 + K0 + kk] = (bf16_t)tile[kk][nn];
        }
    } else if (b == 48) {
#pragma unroll 4
        for (int p = 0; p < 64; p++)
            wepack[p * 256 + tid] = (bf16_t)(TWO_LOG2E * Wemb[p * 256 + tid]);
    } else {
        colc[tid] = 0;
#pragma unroll 4
        for (int p = 0; p < 64; p++)
            bepack[p * 256 + tid] = (bf16_t)(TWO_LOG2E * bemb[p * 256 + tid]);
        // wg1pk[lane*32 + ks*16 + te*8 + j] = Wg1[(ks*32+q*8+j)*32 + te*16+n]
#pragma unroll
        for (int jj = 0; jj < 8; jj++) {
            const int p = tid * 8 + jj;               // 0..2047
            const int lane = p >> 5, r = p & 31;
            const int ks = r >> 4, te = (r >> 3) & 1, j = r & 7;
            const int q = lane >> 4, n = lane & 15;
            wg1pk[p] = (bf16_t)Wg1[(ks * 32 + q * 8 + j) * 32 + te * 16 + n];
        }
        if (tid < 64) {                               // pk4[n][4]
            const int n = tid >> 2, s = tid & 3;
            const float v = (s == 0) ? bg1[n] : (s == 1) ? bg1[16 + n]
                          : (s == 2) ? Wg2[n] : Wg2[16 + n];
            pk4[tid] = v;
        }
    }
}

// ---------------------------------------------------------------------------
// K1: degrees, 256 blocks (block j = adjacency row j).
// ---------------------------------------------------------------------------
__global__ __launch_bounds__(256) void k_deg(
    const float* __restrict__ gp, const int* __restrict__ iterp,
    int* __restrict__ colc, float* __restrict__ rsO) {
    __shared__ unsigned long long mk[4];
    const int j = blockIdx.x, t = threadIdx.x;
    const bool thr = (*iterp) > 50;
    float g = 1.0f / (1.0f + expf(-gp[j * 256 + t]));
    if (t == j) g = 1.0f;
    if (thr && !(g > 0.1f)) g = 0.0f;
    const bool nz = (g != 0.0f);
    const unsigned long long bal = __ballot(nz);
    if ((t & 63) == 0) mk[t >> 6] = bal;
    if (nz) atomicAdd(&colc[t], 1);
    __syncthreads();
    if (t == 0) {
        const int rc = (int)(__popcll(mk[0]) + __popcll(mk[1]) +
                             __popcll(mk[2]) + __popcll(mk[3]));
        rsO[j] = rsqrtf((float)(rc < 1 ? 1 : rc));
    }
}

// ---------------------------------------------------------------------------
// K2: M bf16.  Block j, thread t: M[t][j] = adj[j][t]*rsO[j]*rsI[t].
// ---------------------------------------------------------------------------
__global__ __launch_bounds__(256) void k_mkM(
    const float* __restrict__ gp, const int* __restrict__ iterp,
    const int* __restrict__ colc, const float* __restrict__ rsO,
    bf16_t* __restrict__ Mb) {
    const int j = blockIdx.x, t = threadIdx.x;
    const int ci = colc[t];
    const float rsi = rsqrtf((float)(ci < 1 ? 1 : ci));
    float g = 1.0f / (1.0f + expf(-gp[j * 256 + t]));
    if (t == j) g = 1.0f;
    if ((*iterp) > 50 && !(g > 0.1f)) g = 0.0f;
    Mb[t * 256 + j] = (bf16_t)(g * rsO[j] * rsi);
}

// ---------------------------------------------------------------------------
// K3: fused encoder+heads.  512 blocks x 512 thr, 16-row bands.
// ---------------------------------------------------------------------------
__global__ __launch_bounds__(512) void k_ench(
    const float* __restrict__ X, const bf16_t* __restrict__ Wt,
    const float* __restrict__ benc, const float* __restrict__ bmu,
    const float* __restrict__ blv,
    float* __restrict__ MuOut, float* __restrict__ LvOut) {
    __shared__ __align__(16) bf16_t Xs[16 * 264];
    __shared__ __align__(16) bf16_t Hs[16 * 264];
    const bf16_t* Bte = Wt;
    const bf16_t* Btm = Wt + 65536;
    const bf16_t* Btl = Wt + 131072;
    const int tid = threadIdx.x;
    const int r0 = blockIdx.x * 16;
    const int w = tid >> 6;
    const int lane = tid & 63;
    const int n = lane & 15, q = lane >> 4;
    const int cw = w * 32;
    const floatx4 z4 = {0.f, 0.f, 0.f, 0.f};

    {
        const int e0 = tid * 8;
        const int row = e0 >> 8, col = e0 & 255;
        *(bf16x8*)(Xs + row * 264 + col) = cvt8(X + (r0 + row) * 256 + col);
    }
    __syncthreads();

    floatx4 ah[2];
#pragma unroll
    for (int tc = 0; tc < 2; tc++) ah[tc] = z4;
#pragma unroll 2
    for (int k0 = 0; k0 < 256; k0 += 32) {
        const bf16x8 a = *(const bf16x8*)(Xs + n * 264 + k0 + q * 8);
        bf16x8 b[2];
#pragma unroll
        for (int tc = 0; tc < 2; tc++)
            b[tc] = *(const bf16x8*)(Bte + (cw + tc * 16 + n) * 256 + k0 + q * 8);
#pragma unroll
        for (int tc = 0; tc < 2; tc++) ah[tc] = MFMA16(a, b[tc], ah[tc]);
    }
#pragma unroll
    for (int tc = 0; tc < 2; tc++) {
        const int col = cw + tc * 16 + n;
        const float bv = benc[col];
#pragma unroll
        for (int r = 0; r < 4; r++)
            Hs[(q * 4 + r) * 264 + col] = (bf16_t)fmaxf(ah[tc][r] + bv, 0.0f);
    }
    __syncthreads();

    floatx4 am[2], al[2];
#pragma unroll
    for (int tc = 0; tc < 2; tc++) { am[tc] = z4; al[tc] = z4; }
#pragma unroll 2
    for (int k0 = 0; k0 < 256; k0 += 32) {
        const bf16x8 a = *(const bf16x8*)(Hs + n * 264 + k0 + q * 8);
        bf16x8 bm_[2], bl_[2];
#pragma unroll
        for (int tc = 0; tc < 2; tc++) {
            bm_[tc] = *(const bf16x8*)(Btm + (cw + tc * 16 + n) * 256 + k0 + q * 8);
            bl_[tc] = *(const bf16x8*)(Btl + (cw + tc * 16 + n) * 256 + k0 + q * 8);
        }
#pragma unroll
        for (int tc = 0; tc < 2; tc++) {
            am[tc] = MFMA16(a, bm_[tc], am[tc]);
            al[tc] = MFMA16(a, bl_[tc], al[tc]);
        }
    }
#pragma unroll
    for (int tc = 0; tc < 2; tc++) {
        const int col = cw + tc * 16 + n;
        const float bmv = bmu[col], blvv = blv[col];
#pragma unroll
        for (int r = 0; r < 4; r++) {
            const int row = r0 + q * 4 + r;
            MuOut[row * 256 + col] = am[tc][r] + bmv;
            LvOut[row * 256 + col] = al[tc][r] + blvv;
        }
    }
}

// ---------------------------------------------------------------------------
// K4: fused GCN v5.  4096 blocks x 512 thr, 2 batch rows/block, ONE barrier.
//  phase1: z inline from Mu/Lv/Eps; Q = tanh @ Wg1 -> LDS (full-XOR swizzle,
//          conflict-free writes AND reads)
//  phase2: T1 = M @ Q (MFMA) -> in-register relu/Wg2 + reduce-scatter -> V.
// LDS 32 KB; packed wg1pk/pk4 tables replace 36 scalar loads.
// ---------------------------------------------------------------------------
__global__ __launch_bounds__(512, 8) void k_gcn(
    const float* __restrict__ Mu, const float* __restrict__ Lv,
    const float* __restrict__ Eps, const bf16_t* __restrict__ wepack,
    const bf16_t* __restrict__ bepack, const bf16_t* __restrict__ wg1pk,
    const float* __restrict__ pk4, const bf16_t* __restrict__ Mb,
    float* __restrict__ Vout) {
    __shared__ __align__(16) bf16_t smem[64 * 256];
    const int tid = threadIdx.x;
    const int lane = tid & 63;
    const int w = tid >> 6;                 // wave 0..7
    const int n = lane & 15, q = lane >> 4;
    const int bg = blockIdx.x;              // batch pair
    const int xk = (n & 7) ^ ((n >> 3) << 2);   // lane's bank-spread key
    const floatx4 z4 = {0.f, 0.f, 0.f, 0.f};

    // packed W_g1 fragments: 4 x 16B contiguous per lane
    bf16x8 wg1f[2][2];
    {
        const bf16x8* wp = (const bf16x8*)(wg1pk + lane * 32);
        wg1f[0][0] = wp[0]; wg1f[0][1] = wp[1];
        wg1f[1][0] = wp[2]; wg1f[1][1] = wp[3];
    }

    // ---- phase 1: 32 row-tiles over 8 waves = 4 iters (no barrier before) ----
#pragma unroll 2
    for (int it = 0; it < 4; it++) {
        const int rt = w * 4 + it;
        const int bj0 = rt * 16;
        const int bl = bj0 >> 8;            // local batch 0..1
        const int j0 = bj0 & 255;
        const int jA = j0 + n;
        const int gi = bg * 512 + bl * 256 + jA;
        const float zv = fmaf(Eps[gi],
                              __builtin_amdgcn_exp2f(HALF_LOG2E * Lv[gi]),
                              Mu[gi]);     // 2log2e folded into we/be packs
        const bf16x8 we0 = *(const bf16x8*)(wepack + jA * 64 + q * 8);
        const bf16x8 we1 = *(const bf16x8*)(wepack + jA * 64 + 32 + q * 8);
        const bf16x8 be0 = *(const bf16x8*)(bepack + jA * 64 + q * 8);
        const bf16x8 be1 = *(const bf16x8*)(bepack + jA * 64 + 32 + q * 8);
        bf16x8 a0, a1;
#pragma unroll
        for (int j = 0; j < 8; j++) {
            a0[j] = (bf16_t)fast_tanh2(fmaf(zv, (float)we0[j], (float)be0[j]));
            a1[j] = (bf16_t)fast_tanh2(fmaf(zv, (float)we1[j], (float)be1[j]));
        }
        floatx4 c0 = z4, c1 = z4;
        c0 = MFMA16(a0, wg1f[0][0], c0);
        c0 = MFMA16(a1, wg1f[1][0], c0);
        c1 = MFMA16(a0, wg1f[0][1], c1);
        c1 = MFMA16(a1, wg1f[1][1], c1);
        const int j8a = (j0 >> 3) + (q >> 1);
        const int jlo = (q & 1) * 4;
        const int sw = ((j8a ^ xk) << 3) + jlo;
        bf16x4 s0, s1;
#pragma unroll
        for (int r = 0; r < 4; r++) { s0[r] = (bf16_t)c0[r]; s1[r] = (bf16_t)c1[r]; }
        *(bf16x4*)(smem + (bl * 32 + n) * 256 + sw) = s0;        // e = n
        *(bf16x4*)(smem + (bl * 32 + 16 + n) * 256 + sw) = s1;   // e = 16+n
    }
    __syncthreads();

    // ---- phase 2: T1 = M @ Q (wave w: i in [w*32,w*32+32), c in [0,64)) ----
    const int i0 = w * 32;
    floatx4 acc[2][4];
#pragma unroll
    for (int ti = 0; ti < 2; ti++)
#pragma unroll
        for (int tc = 0; tc < 4; tc++) acc[ti][tc] = z4;
#pragma unroll 2
    for (int k0 = 0; k0 < 256; k0 += 32) {
        const int k8 = k0 >> 3;
        bf16x8 a[2], b[4];
#pragma unroll
        for (int ti = 0; ti < 2; ti++)
            a[ti] = *(const bf16x8*)(Mb + (i0 + ti * 16 + n) * 256 + k0 + q * 8);
#pragma unroll
        for (int tc = 0; tc < 4; tc++)
            b[tc] = *(const bf16x8*)(smem + (tc * 16 + n) * 256 +
                                     (((k8 + q) ^ xk) << 3));
#pragma unroll
        for (int ti = 0; ti < 2; ti++)
#pragma unroll
            for (int tc = 0; tc < 4; tc++)
                acc[ti][tc] = MFMA16(a[ti], b[tc], acc[ti][tc]);
    }

    // ---- epilogue: in-register relu+Wg2 contraction + reduce-scatter ----
    const floatx4 pk = *(const floatx4*)(pk4 + n * 4);
    const float b1a = pk[0], b1b = pk[1], w2a = pk[2], w2b = pk[3];
    float v16[16];   // k = bl*8 + ti*4 + r
#pragma unroll
    for (int ti = 0; ti < 2; ti++)
#pragma unroll
        for (int r = 0; r < 4; r++) {
            v16[ti * 4 + r] =
                fmaxf(acc[ti][0][r] + b1a, 0.0f) * w2a +
                fmaxf(acc[ti][1][r] + b1b, 0.0f) * w2b;
            v16[8 + ti * 4 + r] =
                fmaxf(acc[ti][2][r] + b1a, 0.0f) * w2a +
                fmaxf(acc[ti][3][r] + b1b, 0.0f) * w2b;
        }
    const bool h0 = (lane & 1), h1_ = (lane & 2), h2 = (lane & 4), h3 = (lane & 8);
    float v8[8];
#pragma unroll
    for (int p = 0; p < 8; p++) {
        const float keep = h0 ? v16[2 * p + 1] : v16[2 * p];
        const float send = h0 ? v16[2 * p] : v16[2 * p + 1];
        v8[p] = keep + __shfl_xor(send, 1, 64);
    }
    float v4_[4];
#pragma unroll
    for (int p = 0; p < 4; p++) {
        const float keep = h1_ ? v8[2 * p + 1] : v8[2 * p];
        const float send = h1_ ? v8[2 * p] : v8[2 * p + 1];
        v4_[p] = keep + __shfl_xor(send, 2, 64);
    }
    float v2_[2];
#pragma unroll
    for (int p = 0; p < 2; p++) {
        const float keep = h2 ? v4_[2 * p + 1] : v4_[2 * p];
        const float send = h2 ? v4_[2 * p] : v4_[2 * p + 1];
        v2_[p] = keep + __shfl_xor(send, 4, 64);
    }
    {
        const float keep = h3 ? v2_[1] : v2_[0];
        const float send = h3 ? v2_[0] : v2_[1];
        const float vfin = keep + __shfl_xor(send, 8, 64);
        const int i_out = i0 + ((n >> 2) & 1) * 16 + q * 4 + (n & 3);
        Vout[bg * 512 + (n >> 3) * 256 + i_out] = vfin;
    }
}

// ---------------------------------------------------------------------------
// K5: x_hat = V @ M^T + b_g2, in place.  512 blocks, 16-row bands, 8 waves.
// ---------------------------------------------------------------------------
__global__ __launch_bounds__(512) void k_out(
    float* __restrict__ VX, const bf16_t* __restrict__ Mb,
    const float* __restrict__ bg2) {
    __shared__ __align__(16) bf16_t va[16 * 264];
    const int tid = threadIdx.x;
    const int lane = tid & 63;
    const int w = tid >> 6;
    const int n = lane & 15, q = lane >> 4;
    const int r0 = blockIdx.x * 16;

#pragma unroll
    for (int p = 0; p < 2; p++) {
        const int i4 = p * 512 + tid;
        const int row = i4 >> 6, c4 = (i4 & 63) * 4;
        const floatx4 v = *(const floatx4*)(VX + (r0 + row) * 256 + c4);
        bf16x4 s;
#pragma unroll
        for (int r = 0; r < 4; r++) s[r] = (bf16_t)v[r];
        *(bf16x4*)(va + row * 264 + c4) = s;
    }
    __syncthreads();

    const int cw = w * 32;
    const floatx4 z4 = {0.f, 0.f, 0.f, 0.f};
    floatx4 acc[2];
    acc[0] = z4; acc[1] = z4;
#pragma unroll 2
    for (int k0 = 0; k0 < 256; k0 += 32) {
        const bf16x8 a = *(const bf16x8*)(va + n * 264 + k0 + q * 8);
        bf16x8 b[2];
#pragma unroll
        for (int tc = 0; tc < 2; tc++)
            b[tc] = *(const bf16x8*)(Mb + (cw + tc * 16 + n) * 256 + k0 + q * 8);
#pragma unroll
        for (int tc = 0; tc < 2; tc++) acc[tc] = MFMA16(a, b[tc], acc[tc]);
    }
    const float bv = bg2[0];
#pragma unroll
    for (int tc = 0; tc < 2; tc++) {
        const int col = cw + tc * 16 + n;
#pragma unroll
        for (int r = 0; r < 4; r++)
            VX[(r0 + q * 4 + r) * 256 + col] = acc[tc][r] + bv;
    }
}

// ---------------------------------------------------------------------------
// K6: restore the real adjacency (fp32) — runs LAST.
// ---------------------------------------------------------------------------
__global__ __launch_bounds__(256) void k_adj(
    const float* __restrict__ gp, const int* __restrict__ iterp,
    float* __restrict__ adjOut) {
    const int o = blockIdx.x * 256 + threadIdx.x;  // o = j*256 + i
    const int j = o >> 8, i = o & 255;
    float g = 1.0f / (1.0f + expf(-gp[o]));
    if (i == j) g = 1.0f;
    if ((*iterp) > 50 && !(g > 0.1f)) g = 0.0f;
    adjOut[o] = g;
}

// ---------------------------------------------------------------------------
extern "C" void kernel_launch(void* const* d_in, const int* in_sizes, int n_in,
                              void* d_out, int out_size, void* d_ws, size_t ws_size,
                              hipStream_t stream) {
    const float* x    = (const float*)d_in[0];
    const float* eps  = (const float*)d_in[1];
    const float* Wenc = (const float*)d_in[2];
    const float* benc = (const float*)d_in[3];
    const float* Wmu  = (const float*)d_in[4];
    const float* bmu  = (const float*)d_in[5];
    const float* Wlv  = (const float*)d_in[6];
    const float* blv  = (const float*)d_in[7];
    const float* gp   = (const float*)d_in[8];
    const float* Wemb = (const float*)d_in[9];
    const float* bemb = (const float*)d_in[10];
    const float* Wg1  = (const float*)d_in[11];
    const float* bg1  = (const float*)d_in[12];
    const float* Wg2  = (const float*)d_in[13];
    const float* bg2  = (const float*)d_in[14];
    const int*   itr  = (const int*)d_in[15];
    (void)d_ws; (void)ws_size; (void)in_sizes; (void)n_in; (void)out_size;

    float* xhat = (float*)d_out;             // [8192,256] fp32
    float* adjO = xhat + ADJ_OFF;            // [256,256]  fp32
    float* muo  = xhat + MU_OFF;             // [8192,256] fp32
    float* lvo  = xhat + LV_OFF;             // [8192,256] fp32

    // Scratch carved from OUTPUT slots (zero d_ws footprint):
    //  adj slot (256 KB): Mb [0,128K) | wepack [128K,160K) | bepack
    //  [160K,192K) | colc [192K,193K) | rsO [193K,194K) | wg1pk [194K,198K)
    //  | pk4 [198K,198.25K).  Restored by k_adj LAST.
    //  Wt bf16 (384 KB) at xhat byte 4 MB: dead after k_ench.
    char* adjB = (char*)adjO;
    bf16_t* Mb     = (bf16_t*)adjB;
    bf16_t* wepack = (bf16_t*)(adjB + 131072);
    bf16_t* bepack = (bf16_t*)(adjB + 163840);
    int*    colc   = (int*)(adjB + 196608);
    float*  rsO    = (float*)(adjB + 197632);
    bf16_t* wg1pk  = (bf16_t*)(adjB + 198656);
    float*  pk4    = (float*)(adjB + 202752);
    bf16_t* Wt     = (bf16_t*)((char*)d_out + 4194304);

    k_prep<<<dim3(50), dim3(256), 0, stream>>>(Wenc, Wmu, Wlv, Wemb, bemb,
                                               Wg1, bg1, Wg2, Wt, wepack,
                                               bepack, colc, wg1pk, pk4);
    k_deg <<<dim3(256), dim3(256), 0, stream>>>(gp, itr, colc, rsO);
    k_mkM <<<dim3(256), dim3(256), 0, stream>>>(gp, itr, colc, rsO, Mb);
    k_ench<<<dim3(512), dim3(512), 0, stream>>>(x, Wt, benc, bmu, blv, muo, lvo);
    k_gcn <<<dim3(4096), dim3(512), 0, stream>>>(muo, lvo, eps, wepack, bepack,
                                                 wg1pk, pk4, Mb, xhat);
    k_out <<<dim3(512), dim3(512), 0, stream>>>(xhat, Mb, bg2);
    k_adj <<<dim3(256), dim3(256), 0, stream>>>(gp, itr, adjO);
}